// Round 5
// baseline (131.994 us; speedup 1.0000x reference)
//
#include <hip/hip_runtime.h>
#include <math.h>

#define Bz 8
#define Cc 12
#define Ss 784
#define Nn 785
#define Dd 768
#define Hh 28
#define K1 512
#define PATCHNUM 84

#define GRP1 96              // 8 b * 12 colblocks (64 cols each)
#define GRP2 16              // 8 b * 2 halves
#define NCOPY 1200
#define NBLK (GRP1 + GRP2 + NCOPY)   // 1312

__device__ inline float waveSum(float v) {
#pragma unroll
    for (int off = 32; off > 0; off >>= 1) v += __shfl_xor(v, off);
    return v;
}

// monotone float->uint key: descending float order == descending uint order
__device__ inline unsigned int okey(float v) {
    unsigned int u = __float_as_uint(v);
    return (u & 0x80000000u) ? ~u : (u | 0x80000000u);
}

// Exact top-84 selection over s_val[0..783] -> s_sel flags (1 = selected).
// Matches lax.top_k semantics: rank = #{k greater} + #{equal with lower index} < 84.
// MSB-radix threshold descent (4x8bit, early exit on singleton bucket),
// tie quota filled in ascending index order via ballot bitmasks.
// st layout: [0]=rem [2]=pfx [3]=nb [4]=B [5]=excl [6]=histB [7]=T [8]=have
__device__ void topk84(float* s_val, unsigned int* s_key, int* s_hist,
                       unsigned char* s_sel, unsigned long long* s_eq,
                       unsigned int* st, int tid) {
    const int lane = tid & 63;
    const int wid = tid >> 6;
    for (int s = tid; s < Ss; s += 256) s_key[s] = okey(s_val[s]);
    if (tid == 0) { st[0] = PATCHNUM; st[2] = 0; st[3] = 0; st[8] = 0; }
    __syncthreads();

    for (int pass = 0; pass < 4; ++pass) {
        unsigned int rem = st[0], pfx = st[2], nb = st[3], have = st[8];
        if (have) break;                       // uniform (read post-sync)
        s_hist[tid] = 0;
        __syncthreads();
        int shiftP = 8 * (3 - pass);
        for (int s = tid; s < Ss; s += 256) {
            unsigned int k = s_key[s];
            bool match = (nb == 0) ? true : ((k >> (8 * (4 - nb))) == pfx);
            if (match) atomicAdd(&s_hist[(k >> shiftP) & 255u], 1);
        }
        __syncthreads();
        if (tid < 64) {                        // wave 0: find threshold bin
            int base = tid << 2;
            int h0 = s_hist[base + 0], h1 = s_hist[base + 1];
            int h2 = s_hist[base + 2], h3 = s_hist[base + 3];
            int loc = h0 + h1 + h2 + h3;
            int suf = loc;
#pragma unroll
            for (int off = 1; off < 64; off <<= 1) {
                int o = __shfl_down(suf, off);
                if (tid + off < 64) suf += o;
            }
            int excl = suf - loc;              // count of keys in bins above base+3
            int remi = (int)rem;
            int hh[4] = {h3, h2, h1, h0};      // bins descending: base+3 .. base
#pragma unroll
            for (int j = 0; j < 4; ++j) {
                int inc = excl + hh[j];
                if (excl < remi && remi <= inc) {
                    st[4] = (unsigned int)(base + 3 - j);
                    st[5] = (unsigned int)excl;
                    st[6] = (unsigned int)hh[j];
                }
                excl = inc;
            }
        }
        __syncthreads();
        unsigned int B = st[4], excl = st[5], histB = st[6];
        unsigned int npfx = (pfx << 8) | B;
        unsigned int nnb = nb + 1;
        bool last = (pass == 3);
        bool uniq = (histB == 1u) && !last;
        if (uniq) {                            // unique candidate: T = its full key
            for (int s = tid; s < Ss; s += 256) {
                unsigned int k = s_key[s];
                if ((k >> (8 * (4 - nnb))) == npfx) st[7] = k;
            }
        }
        if (tid == 0) {
            st[0] = rem - excl;
            st[2] = npfx;
            st[3] = nnb;
            if (last) st[7] = npfx;            // full 32-bit prefix == T
            st[8] = (last || uniq) ? 1u : 0u;
        }
        __syncthreads();
    }

    unsigned int T = st[7];
    int quota = (int)st[0];                    // = 84 - #{k > T}, >= 1
    for (int s = tid; s < Ss; s += 256) s_sel[s] = (s_key[s] > T) ? 1 : 0;
    for (int q = 0; q < 4; ++q) {              // eq-bitmask per 64-strip
        int s = q * 256 + wid * 64 + lane;
        bool eqv = (s < Ss) && (s_key[s] == T);
        unsigned long long msk = __ballot(eqv);
        int strip = q * 4 + wid;
        if (lane == 0 && strip < 13) s_eq[strip] = msk;
    }
    __syncthreads();
    if (tid == 0) {                            // first `quota` ties by ascending index
        int need = quota;
        for (int strip = 0; strip < 13 && need > 0; ++strip) {
            unsigned long long msk = s_eq[strip];
            while (msk && need > 0) {
                int bpos = __ffsll(msk) - 1;
                s_sel[strip * 64 + bpos] = 1;
                msk &= msk - 1;
                --need;
            }
        }
    }
    __syncthreads();
}

struct G1 {
    float val[Ss];
    unsigned int key[Ss];
    int hist[256];
    unsigned char sel[Ss];
    unsigned long long eq[13];
    unsigned int st[12];
    float m[Ss];
    float pw[Ss];
    float g[K1];
    float part[4][64];
    float w4[4][4];
    float av[4];
    int ai4[4];
    float w1s[4];
};
struct G2 {
    float val[Ss];
    unsigned int key[Ss];
    int hist[256];
    unsigned char sel[Ss];
    unsigned long long eq[13];
    unsigned int st[12];
    int cnt[Ss];
    int cc[Ss];
    int found[64];
};
union SMem { G1 g1; G2 g2; };

__global__ __launch_bounds__(256) void kFused(const float* __restrict__ hs,
                                              const float* __restrict__ x,
                                              const float* __restrict__ w1,
                                              const float* __restrict__ w2,
                                              float* __restrict__ out,
                                              int select_num) {
    __shared__ SMem sm;
    int bid = blockIdx.x;
    int tid = threadIdx.x;
    int lane = tid & 63, wid = tid >> 6;

    if (bid < GRP1) {
        // ---- group 1: stats + 64-col slice of o2, write out row 0 ----
        G1& S = sm.g1;
        int b = bid / 12;
        int colblk = bid % 12;

        for (int s = tid; s < Ss; s += 256) S.m[s] = 0.f;
        __syncthreads();
        for (int c = 0; c < Cc; ++c) {
            const float* xs = x + (size_t)(b * Cc + c) * Nn * Nn + 1;
            for (int s = tid; s < Ss; s += 256) S.val[s] = xs[s];
            __syncthreads();
            topk84(S.val, S.key, S.hist, S.sel, S.eq, S.st, tid);
            for (int s = tid; s < Ss; s += 256) {
                float v = S.val[s];
                S.m[s] += S.sel[s] ? v : 0.7f * v;
            }
            __syncthreads();
        }

        float lsum = 0.f;
        for (int s = tid; s < Ss; s += 256) {
            float mm = S.m[s];
            S.pw[s] = mm / 12.0f;
            lsum += mm;
        }
        lsum = waveSum(lsum);
        if (lane == 0) S.w1s[wid] = lsum;
        __syncthreads();
        float meanm = (S.w1s[0] + S.w1s[1] + S.w1s[2] + S.w1s[3]) / 784.0f;

        float bv = -INFINITY; int bi = Ss;
        for (int s = tid; s < Ss; s += 256) {
            float z = (S.m[s] > meanm) ? S.pw[s] : 0.0f;
            if (z > bv) { bv = z; bi = s; }
        }
#pragma unroll
        for (int off = 32; off > 0; off >>= 1) {
            float ov = __shfl_xor(bv, off);
            int   oi = __shfl_xor(bi, off);
            if (ov > bv || (ov == bv && oi < bi)) { bv = ov; bi = oi; }
        }
        if (lane == 0) { S.av[wid] = bv; S.ai4[wid] = bi; }
        __syncthreads();
        float abv = S.av[0]; int anchor = S.ai4[0];
#pragma unroll
        for (int w = 1; w < 4; ++w) {
            if (S.av[w] > abv || (S.av[w] == abv && S.ai4[w] < anchor)) {
                abv = S.av[w]; anchor = S.ai4[w];
            }
        }

        int ai = anchor / Hh, aj = anchor % Hh;
        float lA = 0.f, lG = 0.f, lp = 0.f, ln2 = 0.f;
        const float PI_F = 3.14159265358979323846f;
        for (int s = tid; s < Ss; s += 256) {
            float pw = S.pw[s];
            int i = s / Hh, j = s % Hh;
            float ri = (float)(i - ai) / 28.0f;
            float rj = (float)(j - aj) / 28.0f;
            float dist = sqrtf(ri * ri + rj * rj);
            float ang = (atan2f(rj, ri) / PI_F + 1.0f) * 0.5f;
            lA += pw * dist;
            lG += pw * ang;
            if (pw > 0.f) lp += pw * pw;
            else if (pw < 0.f) ln2 += pw * pw;
        }
        lA = waveSum(lA); lG = waveSum(lG); lp = waveSum(lp); ln2 = waveSum(ln2);
        if (lane == 0) {
            S.w4[wid][0] = lA; S.w4[wid][1] = lG; S.w4[wid][2] = lp; S.w4[wid][3] = ln2;
        }
        __syncthreads();
        float A   = S.w4[0][0] + S.w4[1][0] + S.w4[2][0] + S.w4[3][0];
        float G   = S.w4[0][1] + S.w4[1][1] + S.w4[2][1] + S.w4[3][1];
        float P2p = S.w4[0][2] + S.w4[1][2] + S.w4[2][2] + S.w4[3][2];
        float P2n = S.w4[0][3] + S.w4[1][3] + S.w4[2][3] + S.w4[3][3];
        float pwA = S.pw[anchor];
        float cp = pwA * P2p, cn = pwA * P2n;

        for (int k = tid; k < K1; k += 256) {
            float v = A * w1[k] + G * w1[K1 + k];
            S.g[k] = cp * fmaxf(v, 0.f) - cn * fmaxf(-v, 0.f);
        }
        __syncthreads();

        int col = colblk * 64 + (tid & 63);
        int kc = tid >> 6;                     // 0..3, 128 k each
        float acc = 0.f;
        const float* w2p = w2 + (size_t)(kc * 128) * Dd + col;
#pragma unroll 8
        for (int kk = 0; kk < 128; ++kk)
            acc += S.g[kc * 128 + kk] * w2p[kk * Dd];
        S.part[kc][tid & 63] = acc;
        __syncthreads();
        if (tid < 64) {
            float o2 = S.part[0][tid] + S.part[1][tid] + S.part[2][tid] + S.part[3][tid];
            float r = (o2 > 0.f) ? o2 : 0.2f * o2;
            size_t off = (size_t)b * Nn * Dd + colblk * 64 + tid;   // row 0
            out[off] = hs[off] + r;
        }
    } else if (bid < GRP1 + GRP2) {
        // ---- group 2: count -> conv -> stable rank -> gather rows ----
        G2& S = sm.g2;
        int u = bid - GRP1;
        int b = u >> 1, half = u & 1;

        for (int s = tid; s < Ss; s += 256) S.cnt[s] = 0;
        for (int r = tid; r < 64; r += 256) S.found[r] = -1;
        __syncthreads();
        for (int c = 0; c < Cc; ++c) {
            const float* xs = x + (size_t)(b * Cc + c) * Nn * Nn + 1;
            for (int s = tid; s < Ss; s += 256) S.val[s] = xs[s];
            __syncthreads();
            topk84(S.val, S.key, S.hist, S.sel, S.eq, S.st, tid);
            for (int s = tid; s < Ss; s += 256) S.cnt[s] += S.sel[s];
            __syncthreads();
        }
        for (int s = tid; s < Ss; s += 256) {
            int i = s / Hh, j = s % Hh;
            int acc = 0;
            for (int di = -1; di <= 1; ++di)
                for (int dj = -1; dj <= 1; ++dj) {
                    int ii = i + di, jj = j + dj;
                    if (ii >= 0 && ii < Hh && jj >= 0 && jj < Hh)
                        acc += ((di == 0) ? 2 : 1) * ((dj == 0) ? 2 : 1) * S.cnt[ii * Hh + jj];
                }
            S.cc[s] = acc;
        }
        __syncthreads();

        int sA = half * 392 + tid;                       // < 784 always
        int sB = (tid < 136) ? (half * 392 + 256 + tid) : -1;
        int vA = S.cc[sA];
        int vB = (sB >= 0) ? S.cc[sB] : 0;
        int rA = 0, rB = 0;
        const int4* p4 = (const int4*)S.cc;
        for (int ch = 0; ch < 49; ++ch) {
            int4 c0 = p4[ch * 4 + 0];
            int4 c1 = p4[ch * 4 + 1];
            int4 c2 = p4[ch * 4 + 2];
            int4 c3 = p4[ch * 4 + 3];
            int c[16] = {c0.x, c0.y, c0.z, c0.w, c1.x, c1.y, c1.z, c1.w,
                         c2.x, c2.y, c2.z, c2.w, c3.x, c3.y, c3.z, c3.w};
#pragma unroll
            for (int u2 = 0; u2 < 16; ++u2) {
                int t = ch * 16 + u2;
                rA += (c[u2] > vA) || (c[u2] == vA && t < sA);
                rB += (c[u2] > vB) || (c[u2] == vB && t < sB);
            }
        }
        if (rA < select_num && rA < 64) S.found[rA] = sA + 1;
        if (sB >= 0 && rB < select_num && rB < 64) S.found[rB] = sB + 1;
        __syncthreads();

        for (int r = 0; r < select_num; ++r) {
            int src = S.found[r];
            if (src < 0) continue;
            const float4* sp = (const float4*)(hs + ((size_t)b * Nn + src) * Dd);
            float4* dp = (float4*)(out + (size_t)Bz * Nn * Dd + ((size_t)b * select_num + r) * Dd);
            if (tid < Dd / 4) dp[tid] = sp[tid];
        }
    } else {
        // ---- group 3: grid-stride copy of rows 1..784 ----
        const size_t totalF4 = (size_t)Bz * Ss * Dd / 4;       // 1,204,224
        const size_t perB   = (size_t)Ss * Dd / 4;             // 150,528
        const size_t rowPit = (size_t)Nn * Dd / 4;             // 150,720
        size_t f = (size_t)(bid - GRP1 - GRP2) * 256 + tid;
        for (; f < totalF4; f += (size_t)NCOPY * 256) {
            size_t b = f / perB;
            size_t r = f - b * perB;
            size_t idx = b * rowPit + (Dd / 4) + r;            // skip row 0
            ((float4*)out)[idx] = ((const float4*)hs)[idx];
        }
    }
}

extern "C" void kernel_launch(void* const* d_in, const int* in_sizes, int n_in,
                              void* d_out, int out_size, void* d_ws, size_t ws_size,
                              hipStream_t stream) {
    const float* hs = (const float*)d_in[0];
    const float* x  = (const float*)d_in[1];
    const float* w1 = (const float*)d_in[2];
    const float* w2 = (const float*)d_in[3];
    float* out = (float*)d_out;

    const int hsN = Bz * Nn * Dd;                       // 4,823,040
    int select_num = (out_size - hsN) / (Bz * Dd);      // = 42

    kFused<<<NBLK, 256, 0, stream>>>(hs, x, w1, w2, out, select_num);
}

// Round 6
// 81.347 us; speedup vs baseline: 1.6226x; 1.6226x over previous
//
#include <hip/hip_runtime.h>
#include <math.h>

#define Bz 8
#define Cc 12
#define Ss 784
#define Nn 785
#define Dd 768
#define Hh 28
#define K1 512
#define PATCHNUM 84

#define GRP1 96              // 8 b * 12 colblocks (64 cols each)
#define GRP2 16              // 8 b * 2 halves
#define NCOPY 1200
#define NBLK (GRP1 + GRP2 + NCOPY)   // 1312

__device__ inline float waveSum(float v) {
#pragma unroll
    for (int off = 32; off > 0; off >>= 1) v += __shfl_xor(v, off);
    return v;
}

// ---------------- Kernel A: per (b,c): top-84 select, new_score, flags ----------------
// grid (Bz*Cc, 4); 1 value per thread. (Proven in R4: ~2-3 us total.)
__global__ __launch_bounds__(256) void kA_score(const float* __restrict__ x,
                                                float* __restrict__ nscore,
                                                unsigned char* __restrict__ flags) {
    int bc = blockIdx.x;
    int quarter = blockIdx.y;                     // 0..3
    int tid = threadIdx.x;
    const float* sc = x + (size_t)bc * Nn * Nn + 1;   // x[b,c,0,1:]
    __shared__ float s_sc[Ss];
    for (int s = tid; s < Ss; s += 256) s_sc[s] = sc[s];
    __syncthreads();

    int s = tid + 256 * quarter;
    bool valid = (s < Ss);
    float v = valid ? s_sc[s] : 0.f;
    int rank = 0;
    const float4* s4 = (const float4*)s_sc;
    for (int chunk = 0; chunk < Ss / 16; ++chunk) {   // 49 chunks of 16
        float4 c0 = s4[chunk * 4 + 0];
        float4 c1 = s4[chunk * 4 + 1];
        float4 c2 = s4[chunk * 4 + 2];
        float4 c3 = s4[chunk * 4 + 3];
        float c[16] = {c0.x, c0.y, c0.z, c0.w, c1.x, c1.y, c1.z, c1.w,
                       c2.x, c2.y, c2.z, c2.w, c3.x, c3.y, c3.z, c3.w};
#pragma unroll
        for (int u = 0; u < 16; ++u) {
            int t = chunk * 16 + u;
            rank += (c[u] > v) || (c[u] == v && t < s);
        }
    }
    if (valid) {
        bool sel = rank < PATCHNUM;               // lax.top_k tie-break: lower index
        flags[(size_t)bc * Ss + s] = sel ? 1 : 0;
        nscore[(size_t)bc * Ss + s] = sel ? v : v * 0.7f;
    }
}

// ---------------- Kernel Rest: everything else, zero intra-kernel deps ----------------
struct G1 {
    float m[Ss];
    float pw[Ss];
    float g[K1];
    float part[4][64];
    float w4[4][4];
    float av[4];
    int   ai4[4];
    float w1s[4];
};
struct G2 {
    int cnt[Ss];
    int cc[Ss];
    int found[64];
};
union SMem { G1 g1; G2 g2; };

__global__ __launch_bounds__(256) void kRest(const float* __restrict__ hs,
                                             const float* __restrict__ nscore,
                                             const unsigned char* __restrict__ flags,
                                             const float* __restrict__ w1,
                                             const float* __restrict__ w2,
                                             float* __restrict__ out,
                                             int select_num) {
    __shared__ SMem sm;
    int bid = blockIdx.x;
    int tid = threadIdx.x;
    int lane = tid & 63, wid = tid >> 6;

    if (bid < GRP1) {
        // ---- group 1: per-b stats + 64-col slice of o2; write out row 0 ----
        G1& S = sm.g1;
        int b = bid / 12;
        int colblk = bid % 12;

        const float* ns = nscore + (size_t)b * Cc * Ss;
        float lsum = 0.f;
        for (int s = tid; s < Ss; s += 256) {
            float m = 0.f;
#pragma unroll
            for (int c = 0; c < Cc; ++c) m += ns[c * Ss + s];
            S.m[s] = m;
            S.pw[s] = m / 12.0f;
            lsum += m;
        }
        lsum = waveSum(lsum);
        if (lane == 0) S.w1s[wid] = lsum;
        __syncthreads();
        float meanm = (S.w1s[0] + S.w1s[1] + S.w1s[2] + S.w1s[3]) / 784.0f;

        // anchor = argmax_s ((m>mean) ? pw : 0), first max wins
        float bv = -INFINITY; int bi = Ss;
        for (int s = tid; s < Ss; s += 256) {
            float z = (S.m[s] > meanm) ? S.pw[s] : 0.0f;
            if (z > bv) { bv = z; bi = s; }
        }
#pragma unroll
        for (int off = 32; off > 0; off >>= 1) {
            float ov = __shfl_xor(bv, off);
            int   oi = __shfl_xor(bi, off);
            if (ov > bv || (ov == bv && oi < bi)) { bv = ov; bi = oi; }
        }
        if (lane == 0) { S.av[wid] = bv; S.ai4[wid] = bi; }
        __syncthreads();
        float abv = S.av[0]; int anchor = S.ai4[0];
#pragma unroll
        for (int w = 1; w < 4; ++w) {
            if (S.av[w] > abv || (S.av[w] == abv && S.ai4[w] < anchor)) {
                abv = S.av[w]; anchor = S.ai4[w];
            }
        }

        int ai = anchor / Hh, aj = anchor % Hh;
        float lA = 0.f, lG = 0.f, lp = 0.f, ln2 = 0.f;
        const float PI_F = 3.14159265358979323846f;
        for (int s = tid; s < Ss; s += 256) {
            float pw = S.pw[s];
            int i = s / Hh, j = s % Hh;
            float ri = (float)(i - ai) / 28.0f;
            float rj = (float)(j - aj) / 28.0f;
            float dist = sqrtf(ri * ri + rj * rj);
            float ang = (atan2f(rj, ri) / PI_F + 1.0f) * 0.5f;
            lA += pw * dist;
            lG += pw * ang;
            if (pw > 0.f) lp += pw * pw;
            else if (pw < 0.f) ln2 += pw * pw;
        }
        lA = waveSum(lA); lG = waveSum(lG); lp = waveSum(lp); ln2 = waveSum(ln2);
        if (lane == 0) {
            S.w4[wid][0] = lA; S.w4[wid][1] = lG; S.w4[wid][2] = lp; S.w4[wid][3] = ln2;
        }
        __syncthreads();
        float A   = S.w4[0][0] + S.w4[1][0] + S.w4[2][0] + S.w4[3][0];
        float G   = S.w4[0][1] + S.w4[1][1] + S.w4[2][1] + S.w4[3][1];
        float P2p = S.w4[0][2] + S.w4[1][2] + S.w4[2][2] + S.w4[3][2];
        float P2n = S.w4[0][3] + S.w4[1][3] + S.w4[2][3] + S.w4[3][3];
        float pwA = S.pw[anchor];
        float cp = pwA * P2p, cn = pwA * P2n;

        for (int k = tid; k < K1; k += 256) {
            float v = A * w1[k] + G * w1[K1 + k];
            S.g[k] = cp * fmaxf(v, 0.f) - cn * fmaxf(-v, 0.f);
        }
        __syncthreads();

        int col = colblk * 64 + lane;
        int kc = wid;                          // 0..3, 128 k each
        float acc = 0.f;
        const float* w2p = w2 + (size_t)(kc * 128) * Dd + col;
#pragma unroll 8
        for (int kk = 0; kk < 128; ++kk)
            acc += S.g[kc * 128 + kk] * w2p[kk * Dd];
        S.part[kc][lane] = acc;
        __syncthreads();
        if (tid < 64) {
            float o2 = S.part[0][tid] + S.part[1][tid] + S.part[2][tid] + S.part[3][tid];
            float r = (o2 > 0.f) ? o2 : 0.2f * o2;
            size_t off = (size_t)b * Nn * Dd + colblk * 64 + tid;   // row 0
            out[off] = hs[off] + r;
        }
    } else if (bid < GRP1 + GRP2) {
        // ---- group 2: count -> conv -> stable rank -> gather rows ----
        G2& S = sm.g2;
        int u = bid - GRP1;
        int b = u >> 1, half = u & 1;

        for (int r = tid; r < 64; r += 256) S.found[r] = -1;
        for (int s = tid; s < Ss; s += 256) {
            int c0 = 0;
#pragma unroll
            for (int c = 0; c < Cc; ++c) c0 += flags[((size_t)b * Cc + c) * Ss + s];
            S.cnt[s] = c0;
        }
        __syncthreads();
        for (int s = tid; s < Ss; s += 256) {
            int i = s / Hh, j = s % Hh;
            int acc = 0;
            for (int di = -1; di <= 1; ++di)
                for (int dj = -1; dj <= 1; ++dj) {
                    int ii = i + di, jj = j + dj;
                    if (ii >= 0 && ii < Hh && jj >= 0 && jj < Hh)
                        acc += ((di == 0) ? 2 : 1) * ((dj == 0) ? 2 : 1) * S.cnt[ii * Hh + jj];
                }
            S.cc[s] = acc;
        }
        __syncthreads();

        int sA = half * 392 + tid;                       // covers [h*392, h*392+256)
        int sB = (tid < 136) ? (half * 392 + 256 + tid) : -1;
        int vA = S.cc[sA];
        int vB = (sB >= 0) ? S.cc[sB] : 0;
        int rA = 0, rB = 0;
        const int4* p4 = (const int4*)S.cc;
        for (int ch = 0; ch < 49; ++ch) {
            int4 c0 = p4[ch * 4 + 0];
            int4 c1 = p4[ch * 4 + 1];
            int4 c2 = p4[ch * 4 + 2];
            int4 c3 = p4[ch * 4 + 3];
            int c[16] = {c0.x, c0.y, c0.z, c0.w, c1.x, c1.y, c1.z, c1.w,
                         c2.x, c2.y, c2.z, c2.w, c3.x, c3.y, c3.z, c3.w};
#pragma unroll
            for (int u2 = 0; u2 < 16; ++u2) {
                int t = ch * 16 + u2;
                rA += (c[u2] > vA) || (c[u2] == vA && t < sA);
                rB += (c[u2] > vB) || (c[u2] == vB && t < sB);
            }
        }
        if (rA < select_num && rA < 64) S.found[rA] = sA + 1;     // +1: patch_idx offset
        if (sB >= 0 && rB < select_num && rB < 64) S.found[rB] = sB + 1;
        __syncthreads();

        for (int r = 0; r < select_num; ++r) {
            int src = S.found[r];
            if (src < 0) continue;                                // other half owns rank r
            const float4* sp = (const float4*)(hs + ((size_t)b * Nn + src) * Dd);
            float4* dp = (float4*)(out + (size_t)Bz * Nn * Dd + ((size_t)b * select_num + r) * Dd);
            if (tid < Dd / 4) dp[tid] = sp[tid];
        }
    } else {
        // ---- group 3: grid-stride copy of rows 1..784 ----
        const size_t totalF4 = (size_t)Bz * Ss * Dd / 4;       // 1,204,224
        const size_t perB   = (size_t)Ss * Dd / 4;             // 150,528
        const size_t rowPit = (size_t)Nn * Dd / 4;             // 150,720
        size_t f = (size_t)(bid - GRP1 - GRP2) * 256 + tid;
        for (; f < totalF4; f += (size_t)NCOPY * 256) {
            size_t b = f / perB;
            size_t r = f - b * perB;
            size_t idx = b * rowPit + (Dd / 4) + r;            // skip row 0
            ((float4*)out)[idx] = ((const float4*)hs)[idx];
        }
    }
}

extern "C" void kernel_launch(void* const* d_in, const int* in_sizes, int n_in,
                              void* d_out, int out_size, void* d_ws, size_t ws_size,
                              hipStream_t stream) {
    const float* hs = (const float*)d_in[0];
    const float* x  = (const float*)d_in[1];
    const float* w1 = (const float*)d_in[2];
    const float* w2 = (const float*)d_in[3];
    float* out = (float*)d_out;

    const int hsN = Bz * Nn * Dd;                       // 4,823,040
    int select_num = (out_size - hsN) / (Bz * Dd);      // = 42

    // workspace carve (bytes)
    char* ws = (char*)d_ws;
    float* nscore = (float*)ws;                                   // 96*784*4 = 301056 B
    unsigned char* flags = (unsigned char*)(ws + 301056);         // 96*784   =  75264 B

    kA_score<<<dim3(Bz * Cc, 4), 256, 0, stream>>>(x, nscore, flags);
    kRest<<<NBLK, 256, 0, stream>>>(hs, nscore, flags, w1, w2, out, select_num);
}

// Round 7
// 79.750 us; speedup vs baseline: 1.6551x; 1.0200x over previous
//
#include <hip/hip_runtime.h>
#include <math.h>

#define Bz 8
#define Cc 12
#define Ss 784
#define Nn 785
#define Dd 768
#define Hh 28
#define K1 512
#define PATCHNUM 84

#define NTOPK (Bz * Cc * 4)          // 384 topk blocks
#define NCPY  4704                   // Bz*Ss*Dd/4 / 256 = 1,204,224/256 exactly
#define NFIRST (NTOPK + NCPY)        // 5088

#define GRP1 96                      // 8 b * 12 colblocks (64 cols each)
#define GRP2 16                      // 8 b * 2 halves
#define NFIN (GRP1 + GRP2)           // 112

__device__ inline float waveSum(float v) {
#pragma unroll
    for (int off = 32; off > 0; off >>= 1) v += __shfl_xor(v, off);
    return v;
}

// ---------------- Kernel 1: topk blocks + independent copy blocks ----------------
// bid < 384:  per (b,c,quarter) top-84 rank -> nscore, flags   (VALU/LDS-bound)
// bid >= 384: copy rows 1..784 of hs -> out, 1 float4/thread    (BW-bound)
__global__ __launch_bounds__(256) void kFirst(const float* __restrict__ hs,
                                              const float* __restrict__ x,
                                              float* __restrict__ nscore,
                                              unsigned char* __restrict__ flags,
                                              float* __restrict__ out) {
    int bid = blockIdx.x;
    int tid = threadIdx.x;

    if (bid < NTOPK) {
        int bc = bid >> 2;
        int quarter = bid & 3;
        const float* sc = x + (size_t)bc * Nn * Nn + 1;   // x[b,c,0,1:]
        __shared__ float s_sc[Ss];
        for (int s = tid; s < Ss; s += 256) s_sc[s] = sc[s];
        __syncthreads();

        int s = tid + 256 * quarter;
        bool valid = (s < Ss);
        float v = valid ? s_sc[s] : 0.f;
        int rank = 0;
        const float4* s4 = (const float4*)s_sc;
        for (int chunk = 0; chunk < Ss / 16; ++chunk) {   // 49 chunks of 16
            float4 c0 = s4[chunk * 4 + 0];
            float4 c1 = s4[chunk * 4 + 1];
            float4 c2 = s4[chunk * 4 + 2];
            float4 c3 = s4[chunk * 4 + 3];
            float c[16] = {c0.x, c0.y, c0.z, c0.w, c1.x, c1.y, c1.z, c1.w,
                           c2.x, c2.y, c2.z, c2.w, c3.x, c3.y, c3.z, c3.w};
#pragma unroll
            for (int u = 0; u < 16; ++u) {
                int t = chunk * 16 + u;
                rank += (c[u] > v) || (c[u] == v && t < s);
            }
        }
        if (valid) {
            bool sel = rank < PATCHNUM;               // lax.top_k tie-break: lower index
            flags[(size_t)bc * Ss + s] = sel ? 1 : 0;
            nscore[(size_t)bc * Ss + s] = sel ? v : v * 0.7f;
        }
    } else {
        const size_t perB   = (size_t)Ss * Dd / 4;             // 150,528
        const size_t rowPit = (size_t)Nn * Dd / 4;             // 150,720
        size_t f = (size_t)(bid - NTOPK) * 256 + tid;          // < 1,204,224
        size_t b = f / perB;
        size_t r = f - b * perB;
        size_t idx = b * rowPit + (Dd / 4) + r;                // skip row 0
        ((float4*)out)[idx] = ((const float4*)hs)[idx];
    }
}

// ---------------- Kernel 2: latency-sensitive finish, quiet machine ----------------
struct G1 {
    float m[Ss];
    float pw[Ss];
    float g[K1];
    float part[4][64];
    float w4[4][4];
    float av[4];
    int   ai4[4];
    float w1s[4];
};
struct G2 {
    int cnt[Ss];
    int cc[Ss];
    int found[64];
};
union SMem { G1 g1; G2 g2; };

__global__ __launch_bounds__(256) void kFin(const float* __restrict__ hs,
                                            const float* __restrict__ nscore,
                                            const unsigned char* __restrict__ flags,
                                            const float* __restrict__ w1,
                                            const float* __restrict__ w2,
                                            float* __restrict__ out,
                                            int select_num) {
    __shared__ SMem sm;
    int bid = blockIdx.x;
    int tid = threadIdx.x;
    int lane = tid & 63, wid = tid >> 6;

    if (bid < GRP1) {
        // ---- group 1: per-b stats + 64-col slice of o2; write out row 0 ----
        G1& S = sm.g1;
        int b = bid / 12;
        int colblk = bid % 12;

        const float* ns = nscore + (size_t)b * Cc * Ss;
        float lsum = 0.f;
        for (int s = tid; s < Ss; s += 256) {
            float m = 0.f;
#pragma unroll
            for (int c = 0; c < Cc; ++c) m += ns[c * Ss + s];
            S.m[s] = m;
            S.pw[s] = m / 12.0f;
            lsum += m;
        }
        lsum = waveSum(lsum);
        if (lane == 0) S.w1s[wid] = lsum;
        __syncthreads();
        float meanm = (S.w1s[0] + S.w1s[1] + S.w1s[2] + S.w1s[3]) / 784.0f;

        // anchor = argmax_s ((m>mean) ? pw : 0), first max wins
        float bv = -INFINITY; int bi = Ss;
        for (int s = tid; s < Ss; s += 256) {
            float z = (S.m[s] > meanm) ? S.pw[s] : 0.0f;
            if (z > bv) { bv = z; bi = s; }
        }
#pragma unroll
        for (int off = 32; off > 0; off >>= 1) {
            float ov = __shfl_xor(bv, off);
            int   oi = __shfl_xor(bi, off);
            if (ov > bv || (ov == bv && oi < bi)) { bv = ov; bi = oi; }
        }
        if (lane == 0) { S.av[wid] = bv; S.ai4[wid] = bi; }
        __syncthreads();
        float abv = S.av[0]; int anchor = S.ai4[0];
#pragma unroll
        for (int w = 1; w < 4; ++w) {
            if (S.av[w] > abv || (S.av[w] == abv && S.ai4[w] < anchor)) {
                abv = S.av[w]; anchor = S.ai4[w];
            }
        }

        int ai = anchor / Hh, aj = anchor % Hh;
        float lA = 0.f, lG = 0.f, lp = 0.f, ln2 = 0.f;
        const float PI_F = 3.14159265358979323846f;
        for (int s = tid; s < Ss; s += 256) {
            float pw = S.pw[s];
            int i = s / Hh, j = s % Hh;
            float ri = (float)(i - ai) / 28.0f;
            float rj = (float)(j - aj) / 28.0f;
            float dist = sqrtf(ri * ri + rj * rj);
            float ang = (atan2f(rj, ri) / PI_F + 1.0f) * 0.5f;
            lA += pw * dist;
            lG += pw * ang;
            if (pw > 0.f) lp += pw * pw;
            else if (pw < 0.f) ln2 += pw * pw;
        }
        lA = waveSum(lA); lG = waveSum(lG); lp = waveSum(lp); ln2 = waveSum(ln2);
        if (lane == 0) {
            S.w4[wid][0] = lA; S.w4[wid][1] = lG; S.w4[wid][2] = lp; S.w4[wid][3] = ln2;
        }
        __syncthreads();
        float A   = S.w4[0][0] + S.w4[1][0] + S.w4[2][0] + S.w4[3][0];
        float G   = S.w4[0][1] + S.w4[1][1] + S.w4[2][1] + S.w4[3][1];
        float P2p = S.w4[0][2] + S.w4[1][2] + S.w4[2][2] + S.w4[3][2];
        float P2n = S.w4[0][3] + S.w4[1][3] + S.w4[2][3] + S.w4[3][3];
        float pwA = S.pw[anchor];
        float cp = pwA * P2p, cn = pwA * P2n;

        for (int k = tid; k < K1; k += 256) {
            float v = A * w1[k] + G * w1[K1 + k];
            S.g[k] = cp * fmaxf(v, 0.f) - cn * fmaxf(-v, 0.f);
        }
        __syncthreads();

        int col = colblk * 64 + lane;
        int kc = wid;                          // 0..3, 128 k each
        float acc = 0.f;
        const float* w2p = w2 + (size_t)(kc * 128) * Dd + col;
#pragma unroll 8
        for (int kk = 0; kk < 128; ++kk)
            acc += S.g[kc * 128 + kk] * w2p[kk * Dd];
        S.part[kc][lane] = acc;
        __syncthreads();
        if (tid < 64) {
            float o2 = S.part[0][tid] + S.part[1][tid] + S.part[2][tid] + S.part[3][tid];
            float r = (o2 > 0.f) ? o2 : 0.2f * o2;
            size_t off = (size_t)b * Nn * Dd + colblk * 64 + tid;   // row 0
            out[off] = hs[off] + r;
        }
    } else {
        // ---- group 2: count -> conv -> stable rank -> gather rows ----
        G2& S = sm.g2;
        int u = bid - GRP1;
        int b = u >> 1, half = u & 1;

        for (int r = tid; r < 64; r += 256) S.found[r] = -1;
        for (int s = tid; s < Ss; s += 256) {
            int c0 = 0;
#pragma unroll
            for (int c = 0; c < Cc; ++c) c0 += flags[((size_t)b * Cc + c) * Ss + s];
            S.cnt[s] = c0;
        }
        __syncthreads();
        for (int s = tid; s < Ss; s += 256) {
            int i = s / Hh, j = s % Hh;
            int acc = 0;
            for (int di = -1; di <= 1; ++di)
                for (int dj = -1; dj <= 1; ++dj) {
                    int ii = i + di, jj = j + dj;
                    if (ii >= 0 && ii < Hh && jj >= 0 && jj < Hh)
                        acc += ((di == 0) ? 2 : 1) * ((dj == 0) ? 2 : 1) * S.cnt[ii * Hh + jj];
                }
            S.cc[s] = acc;
        }
        __syncthreads();

        int sA = half * 392 + tid;                       // [h*392, h*392+256)
        int sB = (tid < 136) ? (half * 392 + 256 + tid) : -1;   // [h*392+256, h*392+392)
        int vA = S.cc[sA];
        int vB = (sB >= 0) ? S.cc[sB] : 0;
        int rA = 0, rB = 0;
        const int4* p4 = (const int4*)S.cc;
        for (int ch = 0; ch < 49; ++ch) {
            int4 c0 = p4[ch * 4 + 0];
            int4 c1 = p4[ch * 4 + 1];
            int4 c2 = p4[ch * 4 + 2];
            int4 c3 = p4[ch * 4 + 3];
            int c[16] = {c0.x, c0.y, c0.z, c0.w, c1.x, c1.y, c1.z, c1.w,
                         c2.x, c2.y, c2.z, c2.w, c3.x, c3.y, c3.z, c3.w};
#pragma unroll
            for (int u2 = 0; u2 < 16; ++u2) {
                int t = ch * 16 + u2;
                rA += (c[u2] > vA) || (c[u2] == vA && t < sA);
                rB += (c[u2] > vB) || (c[u2] == vB && t < sB);
            }
        }
        if (rA < select_num && rA < 64) S.found[rA] = sA + 1;     // +1: patch_idx offset
        if (sB >= 0 && rB < select_num && rB < 64) S.found[rB] = sB + 1;
        __syncthreads();

        // parallel gather over (rank, d4) space; ranks owned by other half skipped
        int totalT = select_num * (Dd / 4);
        for (int t = tid; t < totalT; t += 256) {
            int r = t / (Dd / 4);
            int d = t - r * (Dd / 4);
            int src = S.found[r];
            if (src < 0) continue;
            const float4* sp = (const float4*)(hs + ((size_t)b * Nn + src) * Dd);
            float4* dp = (float4*)(out + (size_t)Bz * Nn * Dd + ((size_t)b * select_num + r) * Dd);
            dp[d] = sp[d];
        }
    }
}

extern "C" void kernel_launch(void* const* d_in, const int* in_sizes, int n_in,
                              void* d_out, int out_size, void* d_ws, size_t ws_size,
                              hipStream_t stream) {
    const float* hs = (const float*)d_in[0];
    const float* x  = (const float*)d_in[1];
    const float* w1 = (const float*)d_in[2];
    const float* w2 = (const float*)d_in[3];
    float* out = (float*)d_out;

    const int hsN = Bz * Nn * Dd;                       // 4,823,040
    int select_num = (out_size - hsN) / (Bz * Dd);      // = 42

    // workspace carve (bytes)
    char* ws = (char*)d_ws;
    float* nscore = (float*)ws;                                   // 96*784*4 = 301056 B
    unsigned char* flags = (unsigned char*)(ws + 301056);         // 96*784   =  75264 B

    kFirst<<<NFIRST, 256, 0, stream>>>(hs, x, nscore, flags, out);
    kFin<<<NFIN, 256, 0, stream>>>(hs, nscore, flags, w1, w2, out, select_num);
}

// Round 8
// 73.162 us; speedup vs baseline: 1.8041x; 1.0901x over previous
//
#include <hip/hip_runtime.h>
#include <math.h>

#define Bz 8
#define Cc 12
#define Ss 784
#define Nn 785
#define Dd 768
#define Hh 28
#define K1 512
#define PATCHNUM 84

#define NTOPK 384                 // 8b * 12c * 4 quarters
#define NG1 96                    // 8b * 12 colblocks
#define NG2 16                    // 8b * 2 halves
#define CPY0 (NTOPK + NG1 + NG2)  // 496
#define NBLK 2048
#define NCPYB (NBLK - CPY0)       // 1552

#define MAGIC 0x5EC7ED42C0FFEE01ULL

__device__ inline float waveSum(float v) {
#pragma unroll
    for (int off = 32; off > 0; off >>= 1) v += __shfl_xor(v, off);
    return v;
}

struct GT { float sc[Ss]; };
struct G1 {
    float m[Ss];
    float pw[Ss];
    float g[K1];
    float part[4][64];
    float w4[4][4];
    float av[4];
    int   ai4[4];
    float w1s[4];
};
struct G2 {
    int cnt[Ss];
    int cc[Ss];
    int found[64];
};
union SMem { GT gt; G1 g1; G2 g2; };

__global__ __launch_bounds__(256, 4) void kAll(const float* __restrict__ hs,
                                               const float* __restrict__ x,
                                               const float* __restrict__ w1,
                                               const float* __restrict__ w2,
                                               float* __restrict__ nscore,
                                               unsigned char* __restrict__ flags,
                                               unsigned long long* __restrict__ ready,
                                               float* __restrict__ out,
                                               int select_num) {
    __shared__ SMem sm;
    int bid = blockIdx.x;
    int tid = threadIdx.x;
    int lane = tid & 63, wid = tid >> 6;

    if (bid < NTOPK) {
        // ======== producers: per (b,c,quarter) top-84 rank -> nscore, flags ========
        int bc = bid >> 2;
        int quarter = bid & 3;
        const float* sc = x + (size_t)bc * Nn * Nn + 1;   // x[b,c,0,1:]
        float* s_sc = sm.gt.sc;
        for (int s = tid; s < Ss; s += 256) s_sc[s] = sc[s];
        __syncthreads();

        int s = tid + 256 * quarter;
        bool valid = (s < Ss);
        float v = valid ? s_sc[s] : 0.f;
        int rank = 0;
        const float4* s4 = (const float4*)s_sc;
        for (int chunk = 0; chunk < Ss / 16; ++chunk) {   // 49 chunks of 16
            float4 c0 = s4[chunk * 4 + 0];
            float4 c1 = s4[chunk * 4 + 1];
            float4 c2 = s4[chunk * 4 + 2];
            float4 c3 = s4[chunk * 4 + 3];
            float c[16] = {c0.x, c0.y, c0.z, c0.w, c1.x, c1.y, c1.z, c1.w,
                           c2.x, c2.y, c2.z, c2.w, c3.x, c3.y, c3.z, c3.w};
#pragma unroll
            for (int u = 0; u < 16; ++u) {
                int t = chunk * 16 + u;
                rank += (c[u] > v) || (c[u] == v && t < s);
            }
        }
        if (valid) {
            bool sel = rank < PATCHNUM;               // lax.top_k tie-break: lower index
            flags[(size_t)bc * Ss + s] = sel ? 1 : 0;
            nscore[(size_t)bc * Ss + s] = sel ? v : v * 0.7f;
        }
        __syncthreads();                              // all stores issued & waited
        if (tid == 0) {
            __threadfence();                          // release to device scope
            atomicExch(&ready[bid], (unsigned long long)MAGIC);
        }
    } else if (bid < CPY0) {
        // ======== consumers: wait for all 384 producers ========
        if (tid < 192) {
            while (atomicAdd(&ready[tid], 0ULL) != MAGIC) __builtin_amdgcn_s_sleep(8);
            while (atomicAdd(&ready[tid + 192], 0ULL) != MAGIC) __builtin_amdgcn_s_sleep(8);
        }
        __threadfence();                              // acquire side
        __syncthreads();

        if (bid < NTOPK + NG1) {
            // ---- group 1: per-b stats + 64-col slice of o2; write out row 0 ----
            G1& S = sm.g1;
            int u0 = bid - NTOPK;
            int b = u0 / 12;
            int colblk = u0 % 12;

            const float* ns = nscore + (size_t)b * Cc * Ss;
            float lsum = 0.f;
            for (int s = tid; s < Ss; s += 256) {
                float m = 0.f;
#pragma unroll
                for (int c = 0; c < Cc; ++c) m += ns[c * Ss + s];
                S.m[s] = m;
                S.pw[s] = m / 12.0f;
                lsum += m;
            }
            lsum = waveSum(lsum);
            if (lane == 0) S.w1s[wid] = lsum;
            __syncthreads();
            float meanm = (S.w1s[0] + S.w1s[1] + S.w1s[2] + S.w1s[3]) / 784.0f;

            // anchor = argmax_s ((m>mean) ? pw : 0), first max wins
            float bv = -INFINITY; int bi = Ss;
            for (int s = tid; s < Ss; s += 256) {
                float z = (S.m[s] > meanm) ? S.pw[s] : 0.0f;
                if (z > bv) { bv = z; bi = s; }
            }
#pragma unroll
            for (int off = 32; off > 0; off >>= 1) {
                float ov = __shfl_xor(bv, off);
                int   oi = __shfl_xor(bi, off);
                if (ov > bv || (ov == bv && oi < bi)) { bv = ov; bi = oi; }
            }
            if (lane == 0) { S.av[wid] = bv; S.ai4[wid] = bi; }
            __syncthreads();
            float abv = S.av[0]; int anchor = S.ai4[0];
#pragma unroll
            for (int w = 1; w < 4; ++w) {
                if (S.av[w] > abv || (S.av[w] == abv && S.ai4[w] < anchor)) {
                    abv = S.av[w]; anchor = S.ai4[w];
                }
            }

            int ai = anchor / Hh, aj = anchor % Hh;
            float lA = 0.f, lG = 0.f, lp = 0.f, ln2 = 0.f;
            const float PI_F = 3.14159265358979323846f;
            for (int s = tid; s < Ss; s += 256) {
                float pw = S.pw[s];
                int i = s / Hh, j = s % Hh;
                float ri = (float)(i - ai) / 28.0f;
                float rj = (float)(j - aj) / 28.0f;
                float dist = sqrtf(ri * ri + rj * rj);
                float ang = (atan2f(rj, ri) / PI_F + 1.0f) * 0.5f;
                lA += pw * dist;
                lG += pw * ang;
                if (pw > 0.f) lp += pw * pw;
                else if (pw < 0.f) ln2 += pw * pw;
            }
            lA = waveSum(lA); lG = waveSum(lG); lp = waveSum(lp); ln2 = waveSum(ln2);
            if (lane == 0) {
                S.w4[wid][0] = lA; S.w4[wid][1] = lG; S.w4[wid][2] = lp; S.w4[wid][3] = ln2;
            }
            __syncthreads();
            float A   = S.w4[0][0] + S.w4[1][0] + S.w4[2][0] + S.w4[3][0];
            float G   = S.w4[0][1] + S.w4[1][1] + S.w4[2][1] + S.w4[3][1];
            float P2p = S.w4[0][2] + S.w4[1][2] + S.w4[2][2] + S.w4[3][2];
            float P2n = S.w4[0][3] + S.w4[1][3] + S.w4[2][3] + S.w4[3][3];
            float pwA = S.pw[anchor];
            float cp = pwA * P2p, cn = pwA * P2n;

            for (int k = tid; k < K1; k += 256) {
                float v = A * w1[k] + G * w1[K1 + k];
                S.g[k] = cp * fmaxf(v, 0.f) - cn * fmaxf(-v, 0.f);
            }
            __syncthreads();

            int col = colblk * 64 + lane;
            int kc = wid;                          // 0..3, 128 k each
            float acc = 0.f;
            const float* w2p = w2 + (size_t)(kc * 128) * Dd + col;
#pragma unroll 8
            for (int kk = 0; kk < 128; ++kk)
                acc += S.g[kc * 128 + kk] * w2p[kk * Dd];
            S.part[kc][lane] = acc;
            __syncthreads();
            if (tid < 64) {
                float o2 = S.part[0][tid] + S.part[1][tid] + S.part[2][tid] + S.part[3][tid];
                float r = (o2 > 0.f) ? o2 : 0.2f * o2;
                size_t off = (size_t)b * Nn * Dd + colblk * 64 + tid;   // row 0
                out[off] = hs[off] + r;
            }
        } else {
            // ---- group 2: count -> conv -> stable rank -> gather rows ----
            G2& S = sm.g2;
            int u = bid - (NTOPK + NG1);
            int b = u >> 1, half = u & 1;

            for (int r = tid; r < 64; r += 256) S.found[r] = -1;
            for (int s = tid; s < Ss; s += 256) {
                int c0 = 0;
#pragma unroll
                for (int c = 0; c < Cc; ++c) c0 += flags[((size_t)b * Cc + c) * Ss + s];
                S.cnt[s] = c0;
            }
            __syncthreads();
            for (int s = tid; s < Ss; s += 256) {
                int i = s / Hh, j = s % Hh;
                int acc = 0;
                for (int di = -1; di <= 1; ++di)
                    for (int dj = -1; dj <= 1; ++dj) {
                        int ii = i + di, jj = j + dj;
                        if (ii >= 0 && ii < Hh && jj >= 0 && jj < Hh)
                            acc += ((di == 0) ? 2 : 1) * ((dj == 0) ? 2 : 1) * S.cnt[ii * Hh + jj];
                    }
                S.cc[s] = acc;
            }
            __syncthreads();

            int sA = half * 392 + tid;                       // [h*392, h*392+256)
            int sB = (tid < 136) ? (half * 392 + 256 + tid) : -1;
            int vA = S.cc[sA];
            int vB = (sB >= 0) ? S.cc[sB] : 0;
            int rA = 0, rB = 0;
            const int4* p4 = (const int4*)S.cc;
            for (int ch = 0; ch < 49; ++ch) {
                int4 c0 = p4[ch * 4 + 0];
                int4 c1 = p4[ch * 4 + 1];
                int4 c2 = p4[ch * 4 + 2];
                int4 c3 = p4[ch * 4 + 3];
                int c[16] = {c0.x, c0.y, c0.z, c0.w, c1.x, c1.y, c1.z, c1.w,
                             c2.x, c2.y, c2.z, c2.w, c3.x, c3.y, c3.z, c3.w};
#pragma unroll
                for (int u2 = 0; u2 < 16; ++u2) {
                    int t = ch * 16 + u2;
                    rA += (c[u2] > vA) || (c[u2] == vA && t < sA);
                    rB += (c[u2] > vB) || (c[u2] == vB && t < sB);
                }
            }
            if (rA < select_num && rA < 64) S.found[rA] = sA + 1;     // +1: patch_idx offset
            if (sB >= 0 && rB < select_num && rB < 64) S.found[rB] = sB + 1;
            __syncthreads();

            int totalT = select_num * (Dd / 4);
            for (int t = tid; t < totalT; t += 256) {
                int r = t / (Dd / 4);
                int d = t - r * (Dd / 4);
                int src = S.found[r];
                if (src < 0) continue;                       // other half owns rank r
                const float4* sp = (const float4*)(hs + ((size_t)b * Nn + src) * Dd);
                float4* dp = (float4*)(out + (size_t)Bz * Nn * Dd + ((size_t)b * select_num + r) * Dd);
                dp[d] = sp[d];
            }
        }
    } else {
        // ======== copy blocks: rows 1..784, grid-stride, unsynced ========
        const unsigned perB   = (unsigned)(Ss * Dd / 4);     // 150,528
        const unsigned rowPit = (unsigned)(Nn * Dd / 4);     // 150,720
        const unsigned totalF4 = (unsigned)Bz * perB;        // 1,204,224
        const float4* src = (const float4*)hs;
        float4* dst = (float4*)out;
        unsigned f = (unsigned)(bid - CPY0) * 256u + (unsigned)tid;
        for (; f < totalF4; f += (unsigned)NCPYB * 256u) {
            unsigned b = f / perB;
            unsigned r = f - b * perB;
            unsigned idx = b * rowPit + (unsigned)(Dd / 4) + r;  // skip row 0
            dst[idx] = src[idx];
        }
    }
}

extern "C" void kernel_launch(void* const* d_in, const int* in_sizes, int n_in,
                              void* d_out, int out_size, void* d_ws, size_t ws_size,
                              hipStream_t stream) {
    const float* hs = (const float*)d_in[0];
    const float* x  = (const float*)d_in[1];
    const float* w1 = (const float*)d_in[2];
    const float* w2 = (const float*)d_in[3];
    float* out = (float*)d_out;

    const int hsN = Bz * Nn * Dd;                       // 4,823,040
    int select_num = (out_size - hsN) / (Bz * Dd);      // = 42

    // workspace carve (bytes)
    char* ws = (char*)d_ws;
    float* nscore = (float*)ws;                                   // 96*784*4 = 301056 B
    unsigned char* flags = (unsigned char*)(ws + 301056);         // 96*784   =  75264 B
    unsigned long long* ready = (unsigned long long*)(ws + 376320); // 384*8  =   3072 B

    kAll<<<NBLK, 256, 0, stream>>>(hs, x, w1, w2, nscore, flags, ready, out, select_num);
}